// Round 5
// baseline (575.197 us; speedup 1.0000x reference)
//
#include <hip/hip_runtime.h>
#include <hip/hip_bf16.h>
#include <math.h>

#define E_EDGES 262144
#define D_FEAT  128
#define H_HID   256
#define NEXP    4

typedef __attribute__((ext_vector_type(8))) short  short8;
typedef __attribute__((ext_vector_type(4))) float  floatx4;

// ws layout:
//   [0..15]              float probsum[4]
//   [32 .. +512K)        ushort w1b[262144]  (bf16, B-fragment-linear)
//   [+16K)               double gwd[128*16]  (gate_w fp64, per-d packed)
#define W1B_OFF0 0
#define W1B_OFF1 65536      // 256*256
#define W1B_OFF2 98304      // +128*256
#define W1B_OFF3 131072     // +128*256

__device__ __forceinline__ unsigned short f2bf(float f) {
    __hip_bfloat16 h = __float2bfloat16(f);       // RNE
    return *reinterpret_cast<unsigned short*>(&h);
}
__device__ __forceinline__ float bf2f(unsigned short s) {
    return __uint_as_float(((unsigned)s) << 16);   // bf16 -> fp32 exact
}

// ---------------------------------------------------------------------------
// Phase 0a: W1 matrices -> bf16 B-fragment-linear layout:
//   w1b[off + ((k>>3)*256 + n)*8 + (k&7)] = bf16(w1[k*256+n])
// ---------------------------------------------------------------------------
__global__ __launch_bounds__(256) void conv_kernel(
    const float* __restrict__ cw1, const float* __restrict__ dw1,
    const float* __restrict__ mw1, const float* __restrict__ aw1,
    unsigned short* __restrict__ w1b)
{
    int r = blockIdx.x;          // 0..1023 global K row
    int n = threadIdx.x;         // 0..255
    const float* src; int k, off;
    if (r < 256)      { src = cw1; k = r;       off = W1B_OFF0; }
    else if (r < 384) { src = dw1; k = r - 256; off = W1B_OFF1; }
    else if (r < 512) { src = mw1; k = r - 384; off = W1B_OFF2; }
    else              { src = aw1; k = r - 512; off = W1B_OFF3; }
    w1b[off + (((k >> 3) * 256 + n) << 3) + (k & 7)] = f2bf(src[k * 256 + n]);
}

// ---------------------------------------------------------------------------
// Phase 0b: gate_w -> fp64 packed per-feature-d:
//   gwd[d*16 + blk*4 + o] = (double)gw[(blk*128 + d)*4 + o]
// ---------------------------------------------------------------------------
__global__ __launch_bounds__(256) void gconv_kernel(
    const float* __restrict__ gw, double* __restrict__ gwd)
{
    int i = blockIdx.x * 256 + threadIdx.x;    // 0..2047
    int d = i >> 4, blk = (i >> 2) & 3, o = i & 3;
    gwd[i] = (double)gw[(blk * 128 + d) * 4 + o];
}

// ---------------------------------------------------------------------------
// Fused kernel. Block = 64 edges (natural order), 4 waves.
//  1. Stage zu/zv rows coalesced in 4 fp32 quarters (zq, 16 KB, reused) and
//     simultaneously emit a bf16 copy (zbf, 32 KB, XOR-swizzled 16B groups).
//  2. Gate: fp64 partials from zq (lane=edge, wave owns 8 d's per quarter,
//     weights via wave-uniform s_load); partial sum through plog (aliases zq);
//     fp64 softmax -> fp32 probs -> argmax (same semantics as passing rounds).
//  3. Experts: 4 sequential MFMA K-loops, A-frags built directly from zbf
//     (zero barriers inside), B-frags register-prefetched from w1b (L2-hot).
//     Keep score where sel==ex; out[e] = pval*score.
// ---------------------------------------------------------------------------
__global__ __launch_bounds__(256, 3) void fused_kernel(
    const float* __restrict__ z, const int* __restrict__ u, const int* __restrict__ v,
    const double* __restrict__ gwd, const float* __restrict__ gb,
    const unsigned short* __restrict__ w1b,
    const float* __restrict__ cb1, const float* __restrict__ cw2, const float* __restrict__ cb2,
    const float* __restrict__ db1, const float* __restrict__ dw2, const float* __restrict__ db2,
    const float* __restrict__ mb1, const float* __restrict__ mw2, const float* __restrict__ mb2,
    const float* __restrict__ ab1, const float* __restrict__ aw2, const float* __restrict__ ab2,
    float* __restrict__ probsum, float* __restrict__ out)
{
    __shared__ unsigned short zbf[128 * 128];   // 32 KB bf16 z, swizzled groups
    __shared__ double pool[2048];               // 16 KB: zq (fp32 quarter) then plog
    __shared__ float red[4][64];
    __shared__ int   s_sel[64];
    __shared__ float s_pv[64];

    float*  zq   = (float*)pool;
    double* plog = pool;

    const int tid  = threadIdx.x;
    const int lane = tid & 63;
    const int wave = __builtin_amdgcn_readfirstlane(tid >> 6);
    const int e0   = blockIdx.x * 64;

    // ---- staging ids: 2 threads per row, 128 rows (0..63 zu, 64..127 zv) ----
    const int r  = tid >> 1;
    const int hh = tid & 1;
    int node = (r < 64) ? u[e0 + r] : v[e0 + r - 64];
    const float* zrow = z + (size_t)node * D_FEAT;

    double gacc[4] = {0.0, 0.0, 0.0, 0.0};

    float4 f[4];
    {
        const float4* src = (const float4*)(zrow + 16 * hh);
        f[0] = src[0]; f[1] = src[1]; f[2] = src[2]; f[3] = src[3];
    }

    for (int Q = 0; Q < 4; ++Q) {
        // ---- write staged quarter: zq fp32 (rot swizzle) + zbf bf16 ----
        {
            const float* ff = (const float*)f;
            #pragma unroll
            for (int jj = 0; jj < 8; ++jj) {
                int dd  = 16 * hh + 2 * jj;
                int rot = (dd + 2 * r) & 31;
                *(float2*)(zq + r * 32 + rot) = make_float2(ff[2 * jj], ff[2 * jj + 1]);
            }
            #pragma unroll
            for (int i = 0; i < 2; ++i) {
                short8 pk;
                #pragma unroll
                for (int j2 = 0; j2 < 8; ++j2)
                    pk[j2] = (short)f2bf(ff[8 * i + j2]);
                int g   = 4 * Q + 2 * hh + i;
                int gsw = (g + r) & 15;
                *(short8*)(zbf + r * 128 + gsw * 8) = pk;
            }
        }
        __syncthreads();
        // ---- prefetch next quarter (overlaps gate compute) ----
        if (Q < 3) {
            const float4* src = (const float4*)(zrow + 32 * (Q + 1) + 16 * hh);
            f[0] = src[0]; f[1] = src[1]; f[2] = src[2]; f[3] = src[3];
        }
        // ---- gate partial: edge = lane, d = 32Q + 8*wave + j ----
        {
            const int base = 8 * wave;
            #pragma unroll
            for (int j = 0; j < 8; j += 2) {
                int dd  = base + j;
                int rot = (dd + 2 * lane) & 31;
                float2 a2 = *(const float2*)(zq + lane * 32 + rot);
                float2 b2 = *(const float2*)(zq + (64 + lane) * 32 + rot);
                const double* W0 = gwd + (size_t)(32 * Q + dd) * 16;
                const double* W1 = W0 + 16;
                {
                    float adf = fabsf(a2.x - b2.x);
                    float mf  = a2.x * b2.x;
                    double a = (double)a2.x, b = (double)b2.x;
                    double ad = (double)adf, m = (double)mf;
                    #pragma unroll
                    for (int o = 0; o < 4; ++o)
                        gacc[o] = fma(m, W0[12 + o], fma(ad, W0[8 + o],
                                  fma(b, W0[4 + o], fma(a, W0[o], gacc[o]))));
                }
                {
                    float adf = fabsf(a2.y - b2.y);
                    float mf  = a2.y * b2.y;
                    double a = (double)a2.y, b = (double)b2.y;
                    double ad = (double)adf, m = (double)mf;
                    #pragma unroll
                    for (int o = 0; o < 4; ++o)
                        gacc[o] = fma(m, W1[12 + o], fma(ad, W1[8 + o],
                                  fma(b, W1[4 + o], fma(a, W1[o], gacc[o]))));
                }
            }
        }
        __syncthreads();
    }

    // ---- partial logits -> plog (aliases zq; all zq reads are behind barrier) ----
    #pragma unroll
    for (int o = 0; o < 4; ++o)
        plog[(wave * 64 + lane) * 4 + o] = gacc[o];
    __syncthreads();

    // ---- gate tail (threads 0..63 == wave 0; identical semantics to r1-r4) ----
    if (tid < 64) {
        double L[4];
        #pragma unroll
        for (int o = 0; o < 4; ++o)
            L[o] = plog[(0 * 64 + tid) * 4 + o] + plog[(1 * 64 + tid) * 4 + o]
                 + plog[(2 * 64 + tid) * 4 + o] + plog[(3 * 64 + tid) * 4 + o];
        double l0 = L[0] + (double)gb[0], l1 = L[1] + (double)gb[1];
        double l2 = L[2] + (double)gb[2], l3 = L[3] + (double)gb[3];
        double mx = fmax(fmax(l0, l1), fmax(l2, l3));
        double e0d = exp(l0 - mx), e1d = exp(l1 - mx), e2d = exp(l2 - mx), e3d = exp(l3 - mx);
        double ssum = e0d + e1d + e2d + e3d;
        float p[4];
        p[0] = (float)(e0d / ssum); p[1] = (float)(e1d / ssum);
        p[2] = (float)(e2d / ssum); p[3] = (float)(e3d / ssum);
        int   sel  = 0;
        float best = p[0];
        #pragma unroll
        for (int k = 1; k < 4; ++k) {          // strict > keeps first index on ties
            if (p[k] > best) { best = p[k]; sel = k; }
        }
        s_sel[tid] = sel;
        s_pv[tid]  = best;
        float q0 = p[0], q1 = p[1], q2 = p[2], q3 = p[3];
        #pragma unroll
        for (int off = 32; off > 0; off >>= 1) {
            q0 += __shfl_down(q0, off);
            q1 += __shfl_down(q1, off);
            q2 += __shfl_down(q2, off);
            q3 += __shfl_down(q3, off);
        }
        if (tid == 0) {
            atomicAdd(&probsum[0], q0); atomicAdd(&probsum[1], q1);
            atomicAdd(&probsum[2], q2); atomicAdd(&probsum[3], q3);
        }
    }
    __syncthreads();

    // ---- expert MLPs ----
    const float* b1s[4] = {cb1, db1, mb1, ab1};
    const float* w2s[4] = {cw2, dw2, mw2, aw2};
    const float* b2s[4] = {cb2, db2, mb2, ab2};
    const int    Fs[4]  = {256, 128, 128, 512};
    const int    offs[4] = {W1B_OFF0, W1B_OFF1, W1B_OFF2, W1B_OFF3};

    const int colA = lane & 15;
    const int quad = lane >> 4;
    const int nb   = wave * 64 + colA;

    float res = 0.0f;

    for (int ex = 0; ex < 4; ++ex) {
        const int F = Fs[ex];
        const short8* wB = (const short8*)(w1b + offs[ex]);
        const int kiters = F >> 5;

        floatx4 acc[4][4];
        #pragma unroll
        for (int t = 0; t < 4; ++t)
            #pragma unroll
            for (int j = 0; j < 4; ++j)
                acc[t][j] = (floatx4)(0.0f);

        short8 pf0 = wB[quad * 256 + nb];
        short8 pf1 = wB[quad * 256 + nb + 16];
        short8 pf2 = wB[quad * 256 + nb + 32];
        short8 pf3 = wB[quad * 256 + nb + 48];

        for (int it = 0; it < kiters; ++it) {
            short8 c0 = pf0, c1 = pf1, c2 = pf2, c3 = pf3;
            if (it + 1 < kiters) {
                int g2 = ((it + 1) << 2) + quad;
                pf0 = wB[g2 * 256 + nb];      pf1 = wB[g2 * 256 + nb + 16];
                pf2 = wB[g2 * 256 + nb + 32]; pf3 = wB[g2 * 256 + nb + 48];
            }

            int k0 = it << 5;
            int region;                       // 0=zu 1=zv 2=diff 3=mul
            if (ex == 0)      region = (k0 < 128) ? 0 : 1;
            else if (ex == 1) region = 2;
            else if (ex == 2) region = 3;
            else              region = k0 >> 7;
            int gbase = ((k0 & 127) >> 3) + quad;   // d-group of 8

            short8 af[4];
            #pragma unroll
            for (int t = 0; t < 4; ++t) {
                int m   = 16 * t + colA;            // edge 0..63
                int gsw = (gbase + m) & 15;
                if (region == 0) {
                    af[t] = *(const short8*)(zbf + m * 128 + gsw * 8);
                } else if (region == 1) {
                    af[t] = *(const short8*)(zbf + (64 + m) * 128 + gsw * 8);
                } else {
                    short8 uu = *(const short8*)(zbf + m * 128 + gsw * 8);
                    short8 vv = *(const short8*)(zbf + (64 + m) * 128 + gsw * 8);
                    short8 o8;
                    #pragma unroll
                    for (int j = 0; j < 8; ++j) {
                        float a = bf2f((unsigned short)uu[j]);
                        float b = bf2f((unsigned short)vv[j]);
                        float val = (region == 2) ? fabsf(a - b) : (a * b);
                        o8[j] = (short)f2bf(val);
                    }
                    af[t] = o8;
                }
            }
            #pragma unroll
            for (int t = 0; t < 4; ++t) {
                acc[t][0] = __builtin_amdgcn_mfma_f32_16x16x32_bf16(af[t], c0, acc[t][0], 0, 0, 0);
                acc[t][1] = __builtin_amdgcn_mfma_f32_16x16x32_bf16(af[t], c1, acc[t][1], 0, 0, 0);
                acc[t][2] = __builtin_amdgcn_mfma_f32_16x16x32_bf16(af[t], c2, acc[t][2], 0, 0, 0);
                acc[t][3] = __builtin_amdgcn_mfma_f32_16x16x32_bf16(af[t], c3, acc[t][3], 0, 0, 0);
            }
        }

        // ---- epilogue for this expert ----
        float b1v[4], w2v[4];
        #pragma unroll
        for (int j = 0; j < 4; ++j) {
            int h = wave * 64 + j * 16 + colA;
            b1v[j] = b1s[ex][h];
            w2v[j] = w2s[ex][h];
        }
        #pragma unroll
        for (int t = 0; t < 4; ++t) {
            #pragma unroll
            for (int rr = 0; rr < 4; ++rr) {
                float s = 0.0f;
                #pragma unroll
                for (int j = 0; j < 4; ++j) {
                    float h = acc[t][j][rr] + b1v[j];
                    s += fmaxf(h, 0.0f) * w2v[j];
                }
                s += __shfl_xor(s, 1);
                s += __shfl_xor(s, 2);
                s += __shfl_xor(s, 4);
                s += __shfl_xor(s, 8);
                if (colA == 0) red[wave][16 * t + quad * 4 + rr] = s;
            }
        }
        __syncthreads();
        if (tid < 64) {
            float sc = red[0][tid] + red[1][tid] + red[2][tid] + red[3][tid] + b2s[ex][0];
            if (s_sel[tid] == ex) res = s_pv[tid] * sc;
        }
        __syncthreads();   // red reused by next expert
    }

    if (tid < 64) out[e0 + tid] = res;
}

// ---------------------------------------------------------------------------
// aux loss (runs after fused kernel fills probsum)
// ---------------------------------------------------------------------------
__global__ void aux_kernel(const float* __restrict__ probsum, float* __restrict__ out)
{
    if (threadIdx.x == 0 && blockIdx.x == 0) {
        float a = 0.0f;
        #pragma unroll
        for (int k = 0; k < 4; ++k) {
            float mean = probsum[k] * (1.0f / (float)E_EDGES);
            a += mean * mean;
        }
        out[E_EDGES] = a * (float)NEXP;
    }
}

extern "C" void kernel_launch(void* const* d_in, const int* in_sizes, int n_in,
                              void* d_out, int out_size, void* d_ws, size_t ws_size,
                              hipStream_t stream)
{
    const float* z   = (const float*)d_in[0];
    const int*   u   = (const int*)d_in[1];
    const int*   v   = (const int*)d_in[2];
    const float* gw  = (const float*)d_in[3];
    const float* gb  = (const float*)d_in[4];
    const float* cw1 = (const float*)d_in[5];
    const float* cb1 = (const float*)d_in[6];
    const float* cw2 = (const float*)d_in[7];
    const float* cb2 = (const float*)d_in[8];
    const float* dw1 = (const float*)d_in[9];
    const float* db1 = (const float*)d_in[10];
    const float* dw2 = (const float*)d_in[11];
    const float* db2 = (const float*)d_in[12];
    const float* mw1 = (const float*)d_in[13];
    const float* mb1 = (const float*)d_in[14];
    const float* mw2 = (const float*)d_in[15];
    const float* mb2 = (const float*)d_in[16];
    const float* aw1 = (const float*)d_in[17];
    const float* ab1 = (const float*)d_in[18];
    const float* aw2 = (const float*)d_in[19];
    const float* ab2 = (const float*)d_in[20];

    float* out = (float*)d_out;
    char*  ws  = (char*)d_ws;

    float*          probsum = (float*)ws;
    unsigned short* w1b     = (unsigned short*)(ws + 32);
    double*         gwd     = (double*)(ws + 32 + 524288);

    hipMemsetAsync(d_ws, 0, 32, stream);

    conv_kernel<<<1024, 256, 0, stream>>>(cw1, dw1, mw1, aw1, w1b);
    gconv_kernel<<<8, 256, 0, stream>>>(gw, gwd);

    fused_kernel<<<E_EDGES / 64, 256, 0, stream>>>(z, u, v, gwd, gb, w1b,
                                                   cb1, cw2, cb2,
                                                   db1, dw2, db2,
                                                   mb1, mw2, mb2,
                                                   ab1, aw2, ab2,
                                                   probsum, out);

    aux_kernel<<<1, 64, 0, stream>>>(probsum, out);
}

// Round 6
// 399.694 us; speedup vs baseline: 1.4391x; 1.4391x over previous
//
#include <hip/hip_runtime.h>
#include <hip/hip_bf16.h>
#include <math.h>

#define N_NODES 50000
#define E_EDGES 262144
#define D_FEAT  128
#define H_HID   256
#define NEXP    4

typedef __attribute__((ext_vector_type(8))) short  short8;
typedef __attribute__((ext_vector_type(4))) float  floatx4;

// ws layout:
//   [0..15]               float probsum[4]
//   [16..31]              unsigned count[4]
//   [32 .. +16E)          int lists[4][E]
//   [+4E)                 float pval[E]
//   [+512K)               ushort w1b[262144]   (bf16, B-fragment-linear)
//   [+16K)                double gwd[128*16]   (gate_w fp64, per-d packed)
//   [+12.8M)              ushort zb[50000*128] (bf16 copy of z)
#define W1B_OFF0 0
#define W1B_OFF1 65536      // 256*256
#define W1B_OFF2 98304      // +128*256
#define W1B_OFF3 131072     // +128*256

__device__ __forceinline__ unsigned short f2bf(float f) {
    __hip_bfloat16 h = __float2bfloat16(f);       // RNE
    return *reinterpret_cast<unsigned short*>(&h);
}
__device__ __forceinline__ float bf2f(unsigned short s) {
    return __uint_as_float(((unsigned)s) << 16);   // bf16 -> fp32 exact
}

// ---------------------------------------------------------------------------
// Phase 0a: W1 matrices -> bf16 B-fragment-linear layout:
//   w1b[off + ((k>>3)*256 + n)*8 + (k&7)] = bf16(w1[k*256+n])
// ---------------------------------------------------------------------------
__global__ __launch_bounds__(256) void conv_kernel(
    const float* __restrict__ cw1, const float* __restrict__ dw1,
    const float* __restrict__ mw1, const float* __restrict__ aw1,
    unsigned short* __restrict__ w1b)
{
    int r = blockIdx.x;          // 0..1023 global K row
    int n = threadIdx.x;         // 0..255
    const float* src; int k, off;
    if (r < 256)      { src = cw1; k = r;       off = W1B_OFF0; }
    else if (r < 384) { src = dw1; k = r - 256; off = W1B_OFF1; }
    else if (r < 512) { src = mw1; k = r - 384; off = W1B_OFF2; }
    else              { src = aw1; k = r - 512; off = W1B_OFF3; }
    w1b[off + (((k >> 3) * 256 + n) << 3) + (k & 7)] = f2bf(src[k * 256 + n]);
}

// ---------------------------------------------------------------------------
// Phase 0b: gate_w -> fp64 packed per-feature-d:
//   gwd[d*16 + blk*4 + o] = (double)gw[(blk*128 + d)*4 + o]
// ---------------------------------------------------------------------------
__global__ __launch_bounds__(256) void gconv_kernel(
    const float* __restrict__ gw, double* __restrict__ gwd)
{
    int i = blockIdx.x * 256 + threadIdx.x;    // 0..2047
    int d = i >> 4, blk = (i >> 2) & 3, o = i & 3;
    gwd[i] = (double)gw[(blk * 128 + d) * 4 + o];
}

// ---------------------------------------------------------------------------
// Phase 0c: z -> bf16 copy (12.8 MB, stays hot in L2/L3 for the expert gather)
// ---------------------------------------------------------------------------
__global__ __launch_bounds__(256) void zconv_kernel(
    const float* __restrict__ z, unsigned short* __restrict__ zb)
{
    int i = blockIdx.x * 256 + threadIdx.x;    // element/4, grid covers 6.4M elems
    float4 f = ((const float4*)z)[i];
    ushort4 o;
    o.x = f2bf(f.x); o.y = f2bf(f.y); o.z = f2bf(f.z); o.w = f2bf(f.w);
    ((ushort4*)zb)[i] = o;
}

// ---------------------------------------------------------------------------
// Phase 1: gate v3. Thread = edge. zu/zv rows in registers (double-buffered
// 32-float chunks, deep dwordx4 pipeline); fp64 weights via wave-uniform
// scalar loads (d is a loop constant). No LDS / no shuffles in the main loop.
// Tail (fp64 softmax, fp32-prob argmax, ballot compaction) identical to the
// passing rounds.
// ---------------------------------------------------------------------------
__global__ __launch_bounds__(256, 3) void gate_kernel(
    const float* __restrict__ z, const int* __restrict__ u, const int* __restrict__ v,
    const double* __restrict__ gwd, const float* __restrict__ gb,
    float* __restrict__ probsum, unsigned* __restrict__ gcount,
    int* __restrict__ lists, float* __restrict__ pval)
{
    const int tid  = threadIdx.x;
    const int lane = tid & 63;
    const int e    = blockIdx.x * 256 + tid;

    const int ue = u[e], ve = v[e];
    const float4* zu4 = (const float4*)(z + (size_t)ue * D_FEAT);
    const float4* zv4 = (const float4*)(z + (size_t)ve * D_FEAT);

    double a0 = 0.0, a1 = 0.0, a2 = 0.0, a3 = 0.0;

    float4 bu[2][8], bv[2][8];
    #pragma unroll
    for (int i = 0; i < 8; ++i) { bu[0][i] = zu4[i]; bv[0][i] = zv4[i]; }

    #pragma unroll
    for (int c = 0; c < 4; ++c) {
        const int cur = c & 1, nxt = cur ^ 1;
        if (c < 3) {
            #pragma unroll
            for (int i = 0; i < 8; ++i) {
                bu[nxt][i] = zu4[(c + 1) * 8 + i];
                bv[nxt][i] = zv4[(c + 1) * 8 + i];
            }
        }
        const float* au = (const float*)&bu[cur][0];
        const float* av = (const float*)&bv[cur][0];
        #pragma unroll
        for (int j = 0; j < 32; ++j) {
            const double* W = gwd + (size_t)(c * 32 + j) * 16;   // uniform -> s_load
            float af = au[j], bf = av[j];
            float adf = fabsf(af - bf);
            float mf  = af * bf;
            double a = (double)af, b = (double)bf, ad = (double)adf, m = (double)mf;
            a0 = fma(m, W[12], fma(ad, W[8],  fma(b, W[4], fma(a, W[0], a0))));
            a1 = fma(m, W[13], fma(ad, W[9],  fma(b, W[5], fma(a, W[1], a1))));
            a2 = fma(m, W[14], fma(ad, W[10], fma(b, W[6], fma(a, W[2], a2))));
            a3 = fma(m, W[15], fma(ad, W[11], fma(b, W[7], fma(a, W[3], a3))));
        }
    }

    // ---- tail: identical semantics to the passing rounds ----
    double l0 = a0 + (double)gb[0], l1 = a1 + (double)gb[1];
    double l2 = a2 + (double)gb[2], l3 = a3 + (double)gb[3];

    double mx = fmax(fmax(l0, l1), fmax(l2, l3));
    double e0 = exp(l0 - mx), e1 = exp(l1 - mx), e2 = exp(l2 - mx), e3 = exp(l3 - mx);
    double s  = e0 + e1 + e2 + e3;
    float p[4];
    p[0] = (float)(e0 / s); p[1] = (float)(e1 / s);
    p[2] = (float)(e2 / s); p[3] = (float)(e3 / s);

    int   sel  = 0;
    float best = p[0];
    #pragma unroll
    for (int k = 1; k < 4; ++k) {            // strict > keeps first index on ties
        if (p[k] > best) { best = p[k]; sel = k; }
    }

    __shared__ float s_ps[4];
    __shared__ int   s_cnt[4];
    __shared__ int   s_base[4];
    if (tid < 4) { s_ps[tid] = 0.0f; s_cnt[tid] = 0; }
    __syncthreads();

    float q0 = p[0], q1 = p[1], q2 = p[2], q3 = p[3];
    #pragma unroll
    for (int off = 32; off > 0; off >>= 1) {
        q0 += __shfl_down(q0, off);
        q1 += __shfl_down(q1, off);
        q2 += __shfl_down(q2, off);
        q3 += __shfl_down(q3, off);
    }
    if (lane == 0) {
        atomicAdd(&s_ps[0], q0); atomicAdd(&s_ps[1], q1);
        atomicAdd(&s_ps[2], q2); atomicAdd(&s_ps[3], q3);
    }

    unsigned long long lt = (lane == 0) ? 0ull : ((~0ull) >> (64 - lane));
    int mywb = 0, myrank = 0;
    #pragma unroll
    for (int k = 0; k < 4; ++k) {
        unsigned long long mask = __ballot(sel == k);
        if (mask) {
            int leader = (int)__ffsll((unsigned long long)mask) - 1;
            int wb = 0;
            if (lane == leader) wb = atomicAdd(&s_cnt[k], (int)__popcll(mask));
            wb = __shfl(wb, leader);
            if (sel == k) { mywb = wb; myrank = (int)__popcll(mask & lt); }
        }
    }
    __syncthreads();

    if (tid < 4) {
        s_base[tid] = (int)atomicAdd(&gcount[tid], (unsigned)s_cnt[tid]);
        atomicAdd(&probsum[tid], s_ps[tid]);
    }
    __syncthreads();

    int pos = s_base[sel] + mywb + myrank;
    lists[sel * E_EDGES + pos] = e;
    pval[e] = best;
}

// ---------------------------------------------------------------------------
// Phase 2: expert MLP v2. Block = 64 edges of ONE expert (grid.y).
// Stage: gather bf16 zu/zv rows (256B granules), write the expert-specific
// feature tile (bf16, XOR-swizzled 16B groups) to LDS once (ex3: two 256-wide
// passes). K-loop: zero barriers, ds_read_b128 A-frags + register-prefetched
// B-frags + 16 MFMA / iter.
// ---------------------------------------------------------------------------
__device__ __forceinline__ short8 bf8_diff(short8 a, short8 b) {
    short8 r;
    #pragma unroll
    for (int j = 0; j < 8; ++j) {
        float x = bf2f((unsigned short)a[j]);
        float y = bf2f((unsigned short)b[j]);
        r[j] = (short)f2bf(fabsf(x - y));
    }
    return r;
}
__device__ __forceinline__ short8 bf8_mul(short8 a, short8 b) {
    short8 r;
    #pragma unroll
    for (int j = 0; j < 8; ++j) {
        float x = bf2f((unsigned short)a[j]);
        float y = bf2f((unsigned short)b[j]);
        r[j] = (short)f2bf(x * y);
    }
    return r;
}

__global__ __launch_bounds__(256) void expert_kernel(
    const unsigned short* __restrict__ zb,
    const int* __restrict__ u, const int* __restrict__ v,
    const unsigned short* __restrict__ w1b,
    const float* __restrict__ cb1, const float* __restrict__ cw2, const float* __restrict__ cb2,
    const float* __restrict__ db1, const float* __restrict__ dw2, const float* __restrict__ db2,
    const float* __restrict__ mb1, const float* __restrict__ mw2, const float* __restrict__ mb2,
    const float* __restrict__ ab1, const float* __restrict__ aw2, const float* __restrict__ ab2,
    const unsigned* __restrict__ gcount, const int* __restrict__ lists,
    const float* __restrict__ pval, float* __restrict__ out)
{
    int ex = blockIdx.y;
    const float *pb1, *pw2, *pb2;
    int F, w1off;
    if (ex == 0)      { pb1 = cb1; pw2 = cw2; pb2 = cb2; F = 256; w1off = W1B_OFF0; }
    else if (ex == 1) { pb1 = db1; pw2 = dw2; pb2 = db2; F = 128; w1off = W1B_OFF1; }
    else if (ex == 2) { pb1 = mb1; pw2 = mw2; pb2 = mb2; F = 128; w1off = W1B_OFF2; }
    else              { pb1 = ab1; pw2 = aw2; pb2 = ab2; F = 512; w1off = W1B_OFF3; }

    unsigned cnt  = gcount[ex];
    unsigned tile = blockIdx.x * 64u;
    if (tile >= cnt) return;
    int nm = (int)min(64u, cnt - tile);

    __shared__ unsigned short feat[64 * 256];   // 32 KB (Kc<=256)
    __shared__ int   s_e[64], s_u[64], s_v[64];
    __shared__ float s_pv[64];
    __shared__ float red[4][64];

    const int tid  = threadIdx.x;
    const int wave = tid >> 6;
    const int lane = tid & 63;
    const int colA = lane & 15;
    const int quad = lane >> 4;

    if (tid < 64) {
        int m = tid;
        int src = (m < nm) ? (int)(tile + m) : (int)tile;   // clamp tail
        int e = lists[ex * E_EDGES + src];
        s_e[m] = e; s_u[m] = u[e]; s_v[m] = v[e]; s_pv[m] = pval[e];
    }
    __syncthreads();

    // ---- gather this block's bf16 rows: thread -> (edge m, 32-d segment) ----
    const int m   = tid >> 2;
    const int seg = tid & 3;
    const short8* pu = (const short8*)(zb + (size_t)s_u[m] * D_FEAT + seg * 32);
    const short8* pv = (const short8*)(zb + (size_t)s_v[m] * D_FEAT + seg * 32);
    short8 ru[4], rv[4];
    #pragma unroll
    for (int j = 0; j < 4; ++j) { ru[j] = pu[j]; rv[j] = pv[j]; }

    const int Kc    = (F < 256) ? 128 : 256;
    const int G     = Kc >> 3;          // 16B groups per row (16 or 32)
    const int npass = (F > 256) ? 2 : 1;
    const int kiters = Kc >> 5;

    const short8* wB = (const short8*)(w1b + w1off);
    const int nb = wave * 64 + colA;

    floatx4 acc[4][4];
    #pragma unroll
    for (int t = 0; t < 4; ++t)
        #pragma unroll
        for (int j = 0; j < 4; ++j)
            acc[t][j] = (floatx4)(0.0f);

    for (int pass = 0; pass < npass; ++pass) {
        if (pass > 0) __syncthreads();          // drain prev pass K-loop reads
        // ---- stage the feature tile for this pass ----
        if (pass == 0) {
            if (ex == 0 || ex == 3) {           // cat: zu groups 0..15, zv 16..31
                #pragma unroll
                for (int j = 0; j < 4; ++j) {
                    int g0 = seg * 4 + j;
                    *(short8*)(&feat[m * Kc + (((g0)      + m) & (G - 1)) * 8]) = ru[j];
                    *(short8*)(&feat[m * Kc + (((g0 + 16) + m) & (G - 1)) * 8]) = rv[j];
                }
            } else if (ex == 1) {
                #pragma unroll
                for (int j = 0; j < 4; ++j) {
                    int g0 = seg * 4 + j;
                    *(short8*)(&feat[m * Kc + ((g0 + m) & (G - 1)) * 8]) = bf8_diff(ru[j], rv[j]);
                }
            } else {
                #pragma unroll
                for (int j = 0; j < 4; ++j) {
                    int g0 = seg * 4 + j;
                    *(short8*)(&feat[m * Kc + ((g0 + m) & (G - 1)) * 8]) = bf8_mul(ru[j], rv[j]);
                }
            }
        } else {                                 // ex3 pass1: diff 0..15, mul 16..31
            #pragma unroll
            for (int j = 0; j < 4; ++j) {
                int g0 = seg * 4 + j;
                *(short8*)(&feat[m * Kc + (((g0)      + m) & (G - 1)) * 8]) = bf8_diff(ru[j], rv[j]);
                *(short8*)(&feat[m * Kc + (((g0 + 16) + m) & (G - 1)) * 8]) = bf8_mul(ru[j], rv[j]);
            }
        }
        __syncthreads();

        // ---- K-loop: barrier-free ----
        short8 pf0, pf1, pf2, pf3;
        {
            int gg = (pass << 5) + quad;
            pf0 = wB[gg * 256 + nb];      pf1 = wB[gg * 256 + nb + 16];
            pf2 = wB[gg * 256 + nb + 32]; pf3 = wB[gg * 256 + nb + 48];
        }
        for (int it = 0; it < kiters; ++it) {
            short8 c0 = pf0, c1 = pf1, c2 = pf2, c3 = pf3;
            if (it + 1 < kiters) {
                int gg = (pass << 5) + ((it + 1) << 2) + quad;
                pf0 = wB[gg * 256 + nb];      pf1 = wB[gg * 256 + nb + 16];
                pf2 = wB[gg * 256 + nb + 32]; pf3 = wB[gg * 256 + nb + 48];
            }
            short8 af[4];
            #pragma unroll
            for (int t = 0; t < 4; ++t) {
                int m2  = 16 * t + colA;
                int gsw = (((it << 2) + quad) + m2) & (G - 1);
                af[t] = *(const short8*)(&feat[m2 * Kc + gsw * 8]);
            }
            #pragma unroll
            for (int t = 0; t < 4; ++t) {
                acc[t][0] = __builtin_amdgcn_mfma_f32_16x16x32_bf16(af[t], c0, acc[t][0], 0, 0, 0);
                acc[t][1] = __builtin_amdgcn_mfma_f32_16x16x32_bf16(af[t], c1, acc[t][1], 0, 0, 0);
                acc[t][2] = __builtin_amdgcn_mfma_f32_16x16x32_bf16(af[t], c2, acc[t][2], 0, 0, 0);
                acc[t][3] = __builtin_amdgcn_mfma_f32_16x16x32_bf16(af[t], c3, acc[t][3], 0, 0, 0);
            }
        }
    }

    // ---- epilogue: hidden = relu(acc + b1[h]); per-edge sum of hidden*w2[h] ----
    float b1v[4], w2v[4];
    #pragma unroll
    for (int j = 0; j < 4; ++j) {
        int h = wave * 64 + j * 16 + colA;
        b1v[j] = pb1[h];
        w2v[j] = pw2[h];
    }

    #pragma unroll
    for (int t = 0; t < 4; ++t) {
        #pragma unroll
        for (int rr = 0; rr < 4; ++rr) {
            float s = 0.0f;
            #pragma unroll
            for (int j = 0; j < 4; ++j) {
                float h = acc[t][j][rr] + b1v[j];
                s += fmaxf(h, 0.0f) * w2v[j];
            }
            s += __shfl_xor(s, 1);
            s += __shfl_xor(s, 2);
            s += __shfl_xor(s, 4);
            s += __shfl_xor(s, 8);
            if (colA == 0) red[wave][16 * t + quad * 4 + rr] = s;
        }
    }
    __syncthreads();

    if (tid < 64) {
        if (tid < nm) {
            float sc = red[0][tid] + red[1][tid] + red[2][tid] + red[3][tid] + pb2[0];
            out[s_e[tid]] = s_pv[tid] * sc;
        }
    }
}

// ---------------------------------------------------------------------------
// Phase 3: aux loss
// ---------------------------------------------------------------------------
__global__ void aux_kernel(const float* __restrict__ probsum, float* __restrict__ out)
{
    if (threadIdx.x == 0 && blockIdx.x == 0) {
        float a = 0.0f;
        #pragma unroll
        for (int k = 0; k < 4; ++k) {
            float mean = probsum[k] * (1.0f / (float)E_EDGES);
            a += mean * mean;
        }
        out[E_EDGES] = a * (float)NEXP;
    }
}

extern "C" void kernel_launch(void* const* d_in, const int* in_sizes, int n_in,
                              void* d_out, int out_size, void* d_ws, size_t ws_size,
                              hipStream_t stream)
{
    const float* z   = (const float*)d_in[0];
    const int*   u   = (const int*)d_in[1];
    const int*   v   = (const int*)d_in[2];
    const float* gw  = (const float*)d_in[3];
    const float* gb  = (const float*)d_in[4];
    const float* cw1 = (const float*)d_in[5];
    const float* cb1 = (const float*)d_in[6];
    const float* cw2 = (const float*)d_in[7];
    const float* cb2 = (const float*)d_in[8];
    const float* dw1 = (const float*)d_in[9];
    const float* db1 = (const float*)d_in[10];
    const float* dw2 = (const float*)d_in[11];
    const float* db2 = (const float*)d_in[12];
    const float* mw1 = (const float*)d_in[13];
    const float* mb1 = (const float*)d_in[14];
    const float* mw2 = (const float*)d_in[15];
    const float* mb2 = (const float*)d_in[16];
    const float* aw1 = (const float*)d_in[17];
    const float* ab1 = (const float*)d_in[18];
    const float* aw2 = (const float*)d_in[19];
    const float* ab2 = (const float*)d_in[20];

    float* out = (float*)d_out;
    char*  ws  = (char*)d_ws;

    float*          probsum = (float*)ws;
    unsigned*       gcount  = (unsigned*)(ws + 16);
    int*            lists   = (int*)(ws + 32);
    float*          pval    = (float*)(ws + 32 + 16ll * E_EDGES);
    unsigned short* w1b     = (unsigned short*)(ws + 32 + 20ll * E_EDGES);
    double*         gwd     = (double*)(ws + 32 + 20ll * E_EDGES + 524288);
    unsigned short* zb      = (unsigned short*)(ws + 32 + 20ll * E_EDGES + 524288 + 16384);

    hipMemsetAsync(d_ws, 0, 32, stream);

    conv_kernel<<<1024, 256, 0, stream>>>(cw1, dw1, mw1, aw1, w1b);
    gconv_kernel<<<8, 256, 0, stream>>>(gw, gwd);
    zconv_kernel<<<(N_NODES * D_FEAT / 4) / 256, 256, 0, stream>>>(z, zb);

    gate_kernel<<<E_EDGES / 256, 256, 0, stream>>>(z, u, v, gwd, gb,
                                                   probsum, gcount, lists, pval);

    aux_kernel<<<1, 64, 0, stream>>>(probsum, out);

    dim3 g2(E_EDGES / 64, 4);
    expert_kernel<<<g2, 256, 0, stream>>>(zb, u, v, w1b,
                                          cb1, cw2, cb2,
                                          db1, dw2, db2,
                                          mb1, mw2, mb2,
                                          ab1, aw2, ab2,
                                          gcount, lists, pval, out);
}

// Round 7
// 379.803 us; speedup vs baseline: 1.5145x; 1.0524x over previous
//
#include <hip/hip_runtime.h>
#include <hip/hip_bf16.h>
#include <math.h>

#define N_NODES 50000
#define E_EDGES 262144
#define D_FEAT  128
#define H_HID   256
#define NEXP    4

typedef __attribute__((ext_vector_type(8))) short  short8;
typedef __attribute__((ext_vector_type(4))) float  floatx4;

// ws layout:
//   [0..15]               float probsum[4]
//   [16..31]              unsigned count[4]
//   [32 .. +16E)          int lists[4][E]
//   [+4E)                 float pval[E]
//   [+512K)               ushort w1b[262144]   (bf16, B-fragment-linear)
//   [+16K)                double gwd[128*16]   (gate_w fp64, per-d packed)
//   [+12.8M)              ushort zb[50000*128] (bf16 copy of z)
#define W1B_OFF0 0
#define W1B_OFF1 65536      // 256*256
#define W1B_OFF2 98304      // +128*256
#define W1B_OFF3 131072     // +128*256

__device__ __forceinline__ unsigned short f2bf(float f) {
    __hip_bfloat16 h = __float2bfloat16(f);       // RNE
    return *reinterpret_cast<unsigned short*>(&h);
}
__device__ __forceinline__ float bf2f(unsigned short s) {
    return __uint_as_float(((unsigned)s) << 16);   // bf16 -> fp32 exact
}

// ---------------------------------------------------------------------------
// Phase 0a: W1 matrices -> bf16 B-fragment-linear layout:
//   w1b[off + ((k>>3)*256 + n)*8 + (k&7)] = bf16(w1[k*256+n])
// ---------------------------------------------------------------------------
__global__ __launch_bounds__(256) void conv_kernel(
    const float* __restrict__ cw1, const float* __restrict__ dw1,
    const float* __restrict__ mw1, const float* __restrict__ aw1,
    unsigned short* __restrict__ w1b)
{
    int r = blockIdx.x;          // 0..1023 global K row
    int n = threadIdx.x;         // 0..255
    const float* src; int k, off;
    if (r < 256)      { src = cw1; k = r;       off = W1B_OFF0; }
    else if (r < 384) { src = dw1; k = r - 256; off = W1B_OFF1; }
    else if (r < 512) { src = mw1; k = r - 384; off = W1B_OFF2; }
    else              { src = aw1; k = r - 512; off = W1B_OFF3; }
    w1b[off + (((k >> 3) * 256 + n) << 3) + (k & 7)] = f2bf(src[k * 256 + n]);
}

// ---------------------------------------------------------------------------
// Phase 0b: gate_w -> fp64 packed per-feature-d:
//   gwd[d*16 + blk*4 + o] = (double)gw[(blk*128 + d)*4 + o]
// ---------------------------------------------------------------------------
__global__ __launch_bounds__(256) void gconv_kernel(
    const float* __restrict__ gw, double* __restrict__ gwd)
{
    int i = blockIdx.x * 256 + threadIdx.x;    // 0..2047
    int d = i >> 4, blk = (i >> 2) & 3, o = i & 3;
    gwd[i] = (double)gw[(blk * 128 + d) * 4 + o];
}

// ---------------------------------------------------------------------------
// Phase 0c: z -> bf16 copy (12.8 MB, stays hot in L2/L3 for the expert gather)
// ---------------------------------------------------------------------------
__global__ __launch_bounds__(256) void zconv_kernel(
    const float* __restrict__ z, unsigned short* __restrict__ zb)
{
    int i = blockIdx.x * 256 + threadIdx.x;    // element/4, grid covers 6.4M elems
    float4 f = ((const float4*)z)[i];
    ushort4 o;
    o.x = f2bf(f.x); o.y = f2bf(f.y); o.z = f2bf(f.z); o.w = f2bf(f.w);
    ((ushort4*)zb)[i] = o;
}

// ---------------------------------------------------------------------------
// Phase 1: gate v4. Thread = edge. 16 chunks of 8 features; chunk staged in
// FOUR NAMED float4 vars (component access only -> guaranteed VGPRs, no
// scratch; r6's pointer-cast array access spilled 171 MB). One chunk
// prefetched ahead. fp64 weights via wave-uniform s_load (d is a loop
// constant). Tail identical to all passing rounds.
// ---------------------------------------------------------------------------
#define GATE_D(fa, fb, Wp) {                                                  \
    float adf = fabsf((fa) - (fb)); float mf = (fa) * (fb);                   \
    double a_ = (double)(fa), b_ = (double)(fb);                              \
    double ad_ = (double)adf, m_ = (double)mf;                                \
    a0 = fma(m_, (Wp)[12], fma(ad_, (Wp)[8],  fma(b_, (Wp)[4], fma(a_, (Wp)[0], a0)))); \
    a1 = fma(m_, (Wp)[13], fma(ad_, (Wp)[9],  fma(b_, (Wp)[5], fma(a_, (Wp)[1], a1)))); \
    a2 = fma(m_, (Wp)[14], fma(ad_, (Wp)[10], fma(b_, (Wp)[6], fma(a_, (Wp)[2], a2)))); \
    a3 = fma(m_, (Wp)[15], fma(ad_, (Wp)[11], fma(b_, (Wp)[7], fma(a_, (Wp)[3], a3)))); }

__global__ __launch_bounds__(256) void gate_kernel(
    const float* __restrict__ z, const int* __restrict__ u, const int* __restrict__ v,
    const double* __restrict__ gwd, const float* __restrict__ gb,
    float* __restrict__ probsum, unsigned* __restrict__ gcount,
    int* __restrict__ lists, float* __restrict__ pval)
{
    const int tid  = threadIdx.x;
    const int lane = tid & 63;
    const int e    = blockIdx.x * 256 + tid;

    const int ue = u[e], ve = v[e];
    const float4* zu4 = (const float4*)(z + (size_t)ue * D_FEAT);
    const float4* zv4 = (const float4*)(z + (size_t)ve * D_FEAT);

    double a0 = 0.0, a1 = 0.0, a2 = 0.0, a3 = 0.0;

    float4 pu0 = zu4[0], pv0 = zv4[0], pu1 = zu4[1], pv1 = zv4[1];

    #pragma unroll
    for (int c = 0; c < 16; ++c) {
        float4 cu0 = pu0, cv0 = pv0, cu1 = pu1, cv1 = pv1;
        if (c < 15) {
            pu0 = zu4[2 * c + 2]; pv0 = zv4[2 * c + 2];
            pu1 = zu4[2 * c + 3]; pv1 = zv4[2 * c + 3];
        }
        const double* W = gwd + (size_t)(c * 8) * 16;   // uniform -> s_load
        GATE_D(cu0.x, cv0.x, W +  0);
        GATE_D(cu0.y, cv0.y, W + 16);
        GATE_D(cu0.z, cv0.z, W + 32);
        GATE_D(cu0.w, cv0.w, W + 48);
        GATE_D(cu1.x, cv1.x, W + 64);
        GATE_D(cu1.y, cv1.y, W + 80);
        GATE_D(cu1.z, cv1.z, W + 96);
        GATE_D(cu1.w, cv1.w, W + 112);
    }

    // ---- tail: identical semantics to the passing rounds ----
    double l0 = a0 + (double)gb[0], l1 = a1 + (double)gb[1];
    double l2 = a2 + (double)gb[2], l3 = a3 + (double)gb[3];

    double mx = fmax(fmax(l0, l1), fmax(l2, l3));
    double e0 = exp(l0 - mx), e1 = exp(l1 - mx), e2 = exp(l2 - mx), e3 = exp(l3 - mx);
    double s  = e0 + e1 + e2 + e3;
    float p[4];
    p[0] = (float)(e0 / s); p[1] = (float)(e1 / s);
    p[2] = (float)(e2 / s); p[3] = (float)(e3 / s);

    int   sel  = 0;
    float best = p[0];
    #pragma unroll
    for (int k = 1; k < 4; ++k) {            // strict > keeps first index on ties
        if (p[k] > best) { best = p[k]; sel = k; }
    }

    __shared__ float s_ps[4];
    __shared__ int   s_cnt[4];
    __shared__ int   s_base[4];
    if (tid < 4) { s_ps[tid] = 0.0f; s_cnt[tid] = 0; }
    __syncthreads();

    float q0 = p[0], q1 = p[1], q2 = p[2], q3 = p[3];
    #pragma unroll
    for (int off = 32; off > 0; off >>= 1) {
        q0 += __shfl_down(q0, off);
        q1 += __shfl_down(q1, off);
        q2 += __shfl_down(q2, off);
        q3 += __shfl_down(q3, off);
    }
    if (lane == 0) {
        atomicAdd(&s_ps[0], q0); atomicAdd(&s_ps[1], q1);
        atomicAdd(&s_ps[2], q2); atomicAdd(&s_ps[3], q3);
    }

    unsigned long long lt = (lane == 0) ? 0ull : ((~0ull) >> (64 - lane));
    int mywb = 0, myrank = 0;
    #pragma unroll
    for (int k = 0; k < 4; ++k) {
        unsigned long long mask = __ballot(sel == k);
        if (mask) {
            int leader = (int)__ffsll((unsigned long long)mask) - 1;
            int wb = 0;
            if (lane == leader) wb = atomicAdd(&s_cnt[k], (int)__popcll(mask));
            wb = __shfl(wb, leader);
            if (sel == k) { mywb = wb; myrank = (int)__popcll(mask & lt); }
        }
    }
    __syncthreads();

    if (tid < 4) {
        s_base[tid] = (int)atomicAdd(&gcount[tid], (unsigned)s_cnt[tid]);
        atomicAdd(&probsum[tid], s_ps[tid]);
    }
    __syncthreads();

    int pos = s_base[sel] + mywb + myrank;
    lists[sel * E_EDGES + pos] = e;
    pval[e] = best;
}

// ---------------------------------------------------------------------------
// Phase 2: expert MLP (unchanged from round 6). Block = 64 edges of ONE
// expert (grid.y). Gather bf16 zu/zv rows, stage expert-specific feature
// tile (XOR-swizzled 16B groups), barrier-free MFMA K-loop.
// ---------------------------------------------------------------------------
__device__ __forceinline__ short8 bf8_diff(short8 a, short8 b) {
    short8 r;
    #pragma unroll
    for (int j = 0; j < 8; ++j) {
        float x = bf2f((unsigned short)a[j]);
        float y = bf2f((unsigned short)b[j]);
        r[j] = (short)f2bf(fabsf(x - y));
    }
    return r;
}
__device__ __forceinline__ short8 bf8_mul(short8 a, short8 b) {
    short8 r;
    #pragma unroll
    for (int j = 0; j < 8; ++j) {
        float x = bf2f((unsigned short)a[j]);
        float y = bf2f((unsigned short)b[j]);
        r[j] = (short)f2bf(x * y);
    }
    return r;
}

__global__ __launch_bounds__(256) void expert_kernel(
    const unsigned short* __restrict__ zb,
    const int* __restrict__ u, const int* __restrict__ v,
    const unsigned short* __restrict__ w1b,
    const float* __restrict__ cb1, const float* __restrict__ cw2, const float* __restrict__ cb2,
    const float* __restrict__ db1, const float* __restrict__ dw2, const float* __restrict__ db2,
    const float* __restrict__ mb1, const float* __restrict__ mw2, const float* __restrict__ mb2,
    const float* __restrict__ ab1, const float* __restrict__ aw2, const float* __restrict__ ab2,
    const unsigned* __restrict__ gcount, const int* __restrict__ lists,
    const float* __restrict__ pval, float* __restrict__ out)
{
    int ex = blockIdx.y;
    const float *pb1, *pw2, *pb2;
    int F, w1off;
    if (ex == 0)      { pb1 = cb1; pw2 = cw2; pb2 = cb2; F = 256; w1off = W1B_OFF0; }
    else if (ex == 1) { pb1 = db1; pw2 = dw2; pb2 = db2; F = 128; w1off = W1B_OFF1; }
    else if (ex == 2) { pb1 = mb1; pw2 = mw2; pb2 = mb2; F = 128; w1off = W1B_OFF2; }
    else              { pb1 = ab1; pw2 = aw2; pb2 = ab2; F = 512; w1off = W1B_OFF3; }

    unsigned cnt  = gcount[ex];
    unsigned tile = blockIdx.x * 64u;
    if (tile >= cnt) return;
    int nm = (int)min(64u, cnt - tile);

    __shared__ unsigned short feat[64 * 256];   // 32 KB (Kc<=256)
    __shared__ int   s_e[64], s_u[64], s_v[64];
    __shared__ float s_pv[64];
    __shared__ float red[4][64];

    const int tid  = threadIdx.x;
    const int wave = tid >> 6;
    const int lane = tid & 63;
    const int colA = lane & 15;
    const int quad = lane >> 4;

    if (tid < 64) {
        int m = tid;
        int src = (m < nm) ? (int)(tile + m) : (int)tile;   // clamp tail
        int e = lists[ex * E_EDGES + src];
        s_e[m] = e; s_u[m] = u[e]; s_v[m] = v[e]; s_pv[m] = pval[e];
    }
    __syncthreads();

    // ---- gather this block's bf16 rows: thread -> (edge m, 32-d segment) ----
    const int m   = tid >> 2;
    const int seg = tid & 3;
    const short8* pu = (const short8*)(zb + (size_t)s_u[m] * D_FEAT + seg * 32);
    const short8* pv = (const short8*)(zb + (size_t)s_v[m] * D_FEAT + seg * 32);
    short8 ru[4], rv[4];
    #pragma unroll
    for (int j = 0; j < 4; ++j) { ru[j] = pu[j]; rv[j] = pv[j]; }

    const int Kc    = (F < 256) ? 128 : 256;
    const int G     = Kc >> 3;          // 16B groups per row (16 or 32)
    const int npass = (F > 256) ? 2 : 1;
    const int kiters = Kc >> 5;

    const short8* wB = (const short8*)(w1b + w1off);
    const int nb = wave * 64 + colA;

    floatx4 acc[4][4];
    #pragma unroll
    for (int t = 0; t < 4; ++t)
        #pragma unroll
        for (int j = 0; j < 4; ++j)
            acc[t][j] = (floatx4)(0.0f);

    for (int pass = 0; pass < npass; ++pass) {
        if (pass > 0) __syncthreads();          // drain prev pass K-loop reads
        // ---- stage the feature tile for this pass ----
        if (pass == 0) {
            if (ex == 0 || ex == 3) {           // cat: zu groups 0..15, zv 16..31
                #pragma unroll
                for (int j = 0; j < 4; ++j) {
                    int g0 = seg * 4 + j;
                    *(short8*)(&feat[m * Kc + (((g0)      + m) & (G - 1)) * 8]) = ru[j];
                    *(short8*)(&feat[m * Kc + (((g0 + 16) + m) & (G - 1)) * 8]) = rv[j];
                }
            } else if (ex == 1) {
                #pragma unroll
                for (int j = 0; j < 4; ++j) {
                    int g0 = seg * 4 + j;
                    *(short8*)(&feat[m * Kc + ((g0 + m) & (G - 1)) * 8]) = bf8_diff(ru[j], rv[j]);
                }
            } else {
                #pragma unroll
                for (int j = 0; j < 4; ++j) {
                    int g0 = seg * 4 + j;
                    *(short8*)(&feat[m * Kc + ((g0 + m) & (G - 1)) * 8]) = bf8_mul(ru[j], rv[j]);
                }
            }
        } else {                                 // ex3 pass1: diff 0..15, mul 16..31
            #pragma unroll
            for (int j = 0; j < 4; ++j) {
                int g0 = seg * 4 + j;
                *(short8*)(&feat[m * Kc + (((g0)      + m) & (G - 1)) * 8]) = bf8_diff(ru[j], rv[j]);
                *(short8*)(&feat[m * Kc + (((g0 + 16) + m) & (G - 1)) * 8]) = bf8_mul(ru[j], rv[j]);
            }
        }
        __syncthreads();

        // ---- K-loop: barrier-free ----
        short8 pf0, pf1, pf2, pf3;
        {
            int gg = (pass << 5) + quad;
            pf0 = wB[gg * 256 + nb];      pf1 = wB[gg * 256 + nb + 16];
            pf2 = wB[gg * 256 + nb + 32]; pf3 = wB[gg * 256 + nb + 48];
        }
        for (int it = 0; it < kiters; ++it) {
            short8 c0 = pf0, c1 = pf1, c2 = pf2, c3 = pf3;
            if (it + 1 < kiters) {
                int gg = (pass << 5) + ((it + 1) << 2) + quad;
                pf0 = wB[gg * 256 + nb];      pf1 = wB[gg * 256 + nb + 16];
                pf2 = wB[gg * 256 + nb + 32]; pf3 = wB[gg * 256 + nb + 48];
            }
            short8 af[4];
            #pragma unroll
            for (int t = 0; t < 4; ++t) {
                int m2  = 16 * t + colA;
                int gsw = (((it << 2) + quad) + m2) & (G - 1);
                af[t] = *(const short8*)(&feat[m2 * Kc + gsw * 8]);
            }
            #pragma unroll
            for (int t = 0; t < 4; ++t) {
                acc[t][0] = __builtin_amdgcn_mfma_f32_16x16x32_bf16(af[t], c0, acc[t][0], 0, 0, 0);
                acc[t][1] = __builtin_amdgcn_mfma_f32_16x16x32_bf16(af[t], c1, acc[t][1], 0, 0, 0);
                acc[t][2] = __builtin_amdgcn_mfma_f32_16x16x32_bf16(af[t], c2, acc[t][2], 0, 0, 0);
                acc[t][3] = __builtin_amdgcn_mfma_f32_16x16x32_bf16(af[t], c3, acc[t][3], 0, 0, 0);
            }
        }
    }

    // ---- epilogue: hidden = relu(acc + b1[h]); per-edge sum of hidden*w2[h] ----
    float b1v[4], w2v[4];
    #pragma unroll
    for (int j = 0; j < 4; ++j) {
        int h = wave * 64 + j * 16 + colA;
        b1v[j] = pb1[h];
        w2v[j] = pw2[h];
    }

    #pragma unroll
    for (int t = 0; t < 4; ++t) {
        #pragma unroll
        for (int rr = 0; rr < 4; ++rr) {
            float s = 0.0f;
            #pragma unroll
            for (int j = 0; j < 4; ++j) {
                float h = acc[t][j][rr] + b1v[j];
                s += fmaxf(h, 0.0f) * w2v[j];
            }
            s += __shfl_xor(s, 1);
            s += __shfl_xor(s, 2);
            s += __shfl_xor(s, 4);
            s += __shfl_xor(s, 8);
            if (colA == 0) red[wave][16 * t + quad * 4 + rr] = s;
        }
    }
    __syncthreads();

    if (tid < 64) {
        if (tid < nm) {
            float sc = red[0][tid] + red[1][tid] + red[2][tid] + red[3][tid] + pb2[0];
            out[s_e[tid]] = s_pv[tid] * sc;
        }
    }
}

// ---------------------------------------------------------------------------
// Phase 3: aux loss
// ---------------------------------------------------------------------------
__global__ void aux_kernel(const float* __restrict__ probsum, float* __restrict__ out)
{
    if (threadIdx.x == 0 && blockIdx.x == 0) {
        float a = 0.0f;
        #pragma unroll
        for (int k = 0; k < 4; ++k) {
            float mean = probsum[k] * (1.0f / (float)E_EDGES);
            a += mean * mean;
        }
        out[E_EDGES] = a * (float)NEXP;
    }
}

extern "C" void kernel_launch(void* const* d_in, const int* in_sizes, int n_in,
                              void* d_out, int out_size, void* d_ws, size_t ws_size,
                              hipStream_t stream)
{
    const float* z   = (const float*)d_in[0];
    const int*   u   = (const int*)d_in[1];
    const int*   v   = (const int*)d_in[2];
    const float* gw  = (const float*)d_in[3];
    const float* gb  = (const float*)d_in[4];
    const float* cw1 = (const float*)d_in[5];
    const float* cb1 = (const float*)d_in[6];
    const float* cw2 = (const float*)d_in[7];
    const float* cb2 = (const float*)d_in[8];
    const float* dw1 = (const float*)d_in[9];
    const float* db1 = (const float*)d_in[10];
    const float* dw2 = (const float*)d_in[11];
    const float* db2 = (const float*)d_in[12];
    const float* mw1 = (const float*)d_in[13];
    const float* mb1 = (const float*)d_in[14];
    const float* mw2 = (const float*)d_in[15];
    const float* mb2 = (const float*)d_in[16];
    const float* aw1 = (const float*)d_in[17];
    const float* ab1 = (const float*)d_in[18];
    const float* aw2 = (const float*)d_in[19];
    const float* ab2 = (const float*)d_in[20];

    float* out = (float*)d_out;
    char*  ws  = (char*)d_ws;

    float*          probsum = (float*)ws;
    unsigned*       gcount  = (unsigned*)(ws + 16);
    int*            lists   = (int*)(ws + 32);
    float*          pval    = (float*)(ws + 32 + 16ll * E_EDGES);
    unsigned short* w1b     = (unsigned short*)(ws + 32 + 20ll * E_EDGES);
    double*         gwd     = (double*)(ws + 32 + 20ll * E_EDGES + 524288);
    unsigned short* zb      = (unsigned short*)(ws + 32 + 20ll * E_EDGES + 524288 + 16384);

    hipMemsetAsync(d_ws, 0, 32, stream);

    conv_kernel<<<1024, 256, 0, stream>>>(cw1, dw1, mw1, aw1, w1b);
    gconv_kernel<<<8, 256, 0, stream>>>(gw, gwd);
    zconv_kernel<<<(N_NODES * D_FEAT / 4) / 256, 256, 0, stream>>>(z, zb);

    gate_kernel<<<E_EDGES / 256, 256, 0, stream>>>(z, u, v, gwd, gb,
                                                   probsum, gcount, lists, pval);

    aux_kernel<<<1, 64, 0, stream>>>(probsum, out);

    dim3 g2(E_EDGES / 64, 4);
    expert_kernel<<<g2, 256, 0, stream>>>(zb, u, v, w1b,
                                          cb1, cw2, cb2,
                                          db1, dw2, db2,
                                          mb1, mw2, mb2,
                                          ab1, aw2, ab2,
                                          gcount, lists, pval, out);
}